// Round 3
// baseline (312.352 us; speedup 1.0000x reference)
//
#include <hip/hip_runtime.h>
#include <hip/hip_bf16.h>

#define NT 64
#define DM 192
#define NH 6

typedef __attribute__((ext_vector_type(4))) float f32x4;
typedef __attribute__((ext_vector_type(8))) short short8;
typedef __attribute__((ext_vector_type(4))) float float4v;
typedef __attribute__((ext_vector_type(4))) unsigned short ushort4v;
typedef __attribute__((ext_vector_type(8))) unsigned short ushort8v;

// ws layout (bytes)
#define WFRAG_OFF 0
#define BIAS_OFF  147456      // 8*6*3*64*16
#define TAB_OFF   6438912     // BIAS_OFF + 64*6*4*4*64*4*4
#define SCALE_OFF 6444312     // TAB_OFF + 225*6*4

__device__ __forceinline__ unsigned short f2bf(float f){
  unsigned u = __float_as_uint(f);
  u += 0x7fffu + ((u >> 16) & 1u);
  return (unsigned short)(u >> 16);
}
__device__ __forceinline__ float bf2f(unsigned short u){
  return __uint_as_float(((unsigned)u) << 16);
}

// ---------------- precompute A: weight frags + rpb-mlp table + scales ----------------
__global__ __launch_bounds__(256) void pre_a(
  const float* __restrict__ q1w, const float* __restrict__ q2w,
  const float* __restrict__ k1w, const float* __restrict__ k2w,
  const float* __restrict__ v1w, const float* __restrict__ v2w,
  const float* __restrict__ p1w, const float* __restrict__ p2w,
  const float* __restrict__ w1, const float* __restrict__ b1,
  const float* __restrict__ w2, const float* __restrict__ rpbt,
  const float* __restrict__ ls, char* __restrict__ ws)
{
  int blk = blockIdx.x, t = threadIdx.x;
  if (blk < 48) {
    const float* Ws[8] = {q1w,q2w,k1w,k2w,v1w,v2w,p1w,p2w};
    int mat = blk / 6, cb = blk % 6;
    if (t < 192) {
      int lane = t & 63, ks = t >> 6;
      const float* W = Ws[mat];
      int row = (lane & 15) + 16*cb;        // output column (B-col) of this half
      int k0  = 32*ks + 8*(lane >> 4);      // k run
      unsigned short tmp[8];
      #pragma unroll
      for (int i = 0; i < 8; ++i) tmp[i] = f2bf(W[row*96 + k0 + i]);
      *(ushort8v*)(ws + (size_t)((mat*6+cb)*3+ks)*1024 + lane*16) = *(ushort8v*)tmp;
    }
  } else {
    // rpb mlp: 225 positions -> 6 heads
    float* tab = (float*)(ws + TAB_OFF);
    if (t < 225) {
      float t0 = rpbt[2*t], t1 = rpbt[2*t+1];
      float acc[6] = {0,0,0,0,0,0};
      for (int j = 0; j < 128; ++j) {
        float hv = fmaxf(t0*w1[2*j] + t1*w1[2*j+1] + b1[j], 0.f);
        #pragma unroll
        for (int hh = 0; hh < 6; ++hh) acc[hh] += hv * w2[hh*128 + j];
      }
      #pragma unroll
      for (int hh = 0; hh < 6; ++hh) tab[t*6 + hh] = acc[hh];
    }
    if (t >= 240 && t < 246) {
      float* sc = (float*)(ws + SCALE_OFF);
      int i = t - 240;
      sc[i] = expf(fminf(ls[i], 4.605170185988091f)); // log(100)
    }
  }
}

// ---------------- precompute B: fused bias = 16*sigmoid(rpb) + mask, fragment order ----------------
__global__ __launch_bounds__(256) void pre_b(
  const float* __restrict__ mask, const int* __restrict__ rpi,
  char* __restrict__ ws)
{
  int w = blockIdx.x / 6, h = blockIdx.x % 6;
  int lane = threadIdx.x & 63, ct = threadIdx.x >> 6;
  const float* tab = (const float*)(ws + TAB_OFF);
  float* bias = (float*)(ws + BIAS_OFF);
  #pragma unroll
  for (int rt = 0; rt < 4; ++rt)
    #pragma unroll
    for (int r = 0; r < 4; ++r) {
      int i = 16*rt + ((lane >> 4) << 2) + r;   // attn row (C/D frag row)
      int j = 16*ct + (lane & 15);              // attn col (C/D frag col)
      int idx = rpi[i*64 + j];
      float tv = tab[idx*6 + h];
      float sg = 16.f / (1.f + expf(-tv));
      float mv = mask[(w*64 + i)*64 + j];
      bias[(size_t)(((w*6+h)*4+rt)*4+ct)*256 + lane*4 + r] = sg + mv;
    }
}

// ---------------- main fused kernel: 1 block = 1 window, 6 waves = 6 heads ----------------
__global__ __launch_bounds__(384) void win_attn(
  const float* __restrict__ x, const char* __restrict__ ws,
  const float* __restrict__ q1b, const float* __restrict__ q2b,
  const float* __restrict__ k1b, const float* __restrict__ k2b,
  const float* __restrict__ v1b, const float* __restrict__ v2b,
  const float* __restrict__ p1b, const float* __restrict__ p2b,
  float* __restrict__ out)
{
  extern __shared__ char smem[];
  unsigned short* xb = (unsigned short*)smem;       // [64][200] bf16 (x, later o)
  const int tid = threadIdx.x;
  const int wv = tid >> 6, lane = tid & 63;
  const int lhi = lane >> 4, llo = lane & 15;
  const int b = blockIdx.x;
  const int w_in = b & 63;
  unsigned short* scr = (unsigned short*)(smem + 25600) + (size_t)wv * 7424;
  unsigned short* qns = scr;                        // [64][40]
  unsigned short* kns = scr + 2560;                 // [64][40]
  unsigned short* vTs = scr + 5120;                 // [32][72] (v^T)
  unsigned short* Ps  = scr;                        // [64][72] overlays qn+kn

  const int h = wv;
  const int half = (h < 3) ? 0 : 1;
  const int cb0 = (h % 3) * 2;
  const f32x4 zf = {0.f, 0.f, 0.f, 0.f};

  // issue x loads first (coalesced float4)
  const float* xg = x + (size_t)b * (NT*DM);
  float4v xv[8];
  #pragma unroll
  for (int it = 0; it < 8; ++it) {
    int f4 = tid + it*384;
    xv[it] = *(const float4v*)(xg + 4*f4);
  }

  // weight B-fragments (global, L2-resident, coalesced 16B/lane)
  short8 bq[2][3], bk[2][3], bv[2][3];
  #pragma unroll
  for (int ct = 0; ct < 2; ++ct)
    #pragma unroll
    for (int ks = 0; ks < 3; ++ks) {
      int cb = cb0 + ct;
      bq[ct][ks] = *(const short8*)(ws + (size_t)(((0+half)*6+cb)*3+ks)*1024 + lane*16);
      bk[ct][ks] = *(const short8*)(ws + (size_t)(((2+half)*6+cb)*3+ks)*1024 + lane*16);
      bv[ct][ks] = *(const short8*)(ws + (size_t)(((4+half)*6+cb)*3+ks)*1024 + lane*16);
    }
  const float* qbp = half ? q2b : q1b;
  const float* kbp = half ? k2b : k1b;
  const float* vbp = half ? v2b : v1b;
  float qbias[2], kbias[2], vbias[2];
  #pragma unroll
  for (int ct = 0; ct < 2; ++ct) {
    int cc = 16*(cb0+ct) + llo;
    qbias[ct] = qbp[cc]; kbias[ct] = kbp[cc]; vbias[ct] = vbp[cc];
  }
  float scale_h = ((const float*)(ws + SCALE_OFF))[h];

  // stage x -> LDS bf16
  #pragma unroll
  for (int it = 0; it < 8; ++it) {
    int f4 = tid + it*384;
    int row = f4 / 48, c4 = f4 % 48;
    ushort4v pk;
    pk[0] = f2bf(xv[it][0]); pk[1] = f2bf(xv[it][1]);
    pk[2] = f2bf(xv[it][2]); pk[3] = f2bf(xv[it][3]);
    *(ushort4v*)(xb + row*200 + c4*4) = pk;
  }
  __syncthreads();

  // ---- Phase A: q,k,v for this head (64x32 each) ----
  #pragma unroll
  for (int rt = 0; rt < 4; ++rt) {
    short8 a[3];
    #pragma unroll
    for (int ks = 0; ks < 3; ++ks)
      a[ks] = *(const short8*)(xb + (16*rt + llo)*200 + half*96 + ks*32 + 8*lhi);
    f32x4 aq2[2], ak2[2], av2[2];
    #pragma unroll
    for (int ct = 0; ct < 2; ++ct) { aq2[ct] = zf; ak2[ct] = zf; av2[ct] = zf; }
    #pragma unroll
    for (int ks = 0; ks < 3; ++ks)
      #pragma unroll
      for (int ct = 0; ct < 2; ++ct) {
        aq2[ct] = __builtin_amdgcn_mfma_f32_16x16x32_bf16(a[ks], bq[ct][ks], aq2[ct], 0,0,0);
        ak2[ct] = __builtin_amdgcn_mfma_f32_16x16x32_bf16(a[ks], bk[ct][ks], ak2[ct], 0,0,0);
        av2[ct] = __builtin_amdgcn_mfma_f32_16x16x32_bf16(a[ks], bv[ct][ks], av2[ct], 0,0,0);
      }
    int r0 = 16*rt + 4*lhi;
    float qv[2][4], kv[2][4], vv[2][4];
    #pragma unroll
    for (int ct = 0; ct < 2; ++ct) {
      int colg = 32*h + 16*ct + llo;
      #pragma unroll
      for (int r = 0; r < 4; ++r) {
        float res = bf2f(xb[(r0+r)*200 + colg]);
        qv[ct][r] = aq2[ct][r] + res + qbias[ct];
        kv[ct][r] = ak2[ct][r] + res + kbias[ct];
        vv[ct][r] = av2[ct][r] + res + vbias[ct];
      }
    }
    #pragma unroll
    for (int r = 0; r < 4; ++r) {
      float sq = qv[0][r]*qv[0][r] + qv[1][r]*qv[1][r];
      float sk = kv[0][r]*kv[0][r] + kv[1][r]*kv[1][r];
      sq += __shfl_xor(sq,1,16); sq += __shfl_xor(sq,2,16);
      sq += __shfl_xor(sq,4,16); sq += __shfl_xor(sq,8,16);
      sk += __shfl_xor(sk,1,16); sk += __shfl_xor(sk,2,16);
      sk += __shfl_xor(sk,4,16); sk += __shfl_xor(sk,8,16);
      float invq = scale_h / fmaxf(sqrtf(sq), 1e-12f);  // fold logit scale into qn
      float invk = 1.f / fmaxf(sqrtf(sk), 1e-12f);
      #pragma unroll
      for (int ct = 0; ct < 2; ++ct) {
        qns[(r0+r)*40 + 16*ct + llo] = f2bf(qv[ct][r]*invq);
        kns[(r0+r)*40 + 16*ct + llo] = f2bf(kv[ct][r]*invk);
        vTs[(16*ct+llo)*72 + (r0+r)] = f2bf(vv[ct][r]);
      }
    }
  }

  // ---- QK^T (K=32, one MFMA per 16x16 tile) ----
  short8 aqf[4], bkf[4];
  #pragma unroll
  for (int i = 0; i < 4; ++i) {
    aqf[i] = *(const short8*)(qns + (16*i + llo)*40 + 8*lhi);
    bkf[i] = *(const short8*)(kns + (16*i + llo)*40 + 8*lhi);
  }
  f32x4 p[4][4];
  #pragma unroll
  for (int rt = 0; rt < 4; ++rt)
    #pragma unroll
    for (int ct = 0; ct < 4; ++ct)
      p[rt][ct] = __builtin_amdgcn_mfma_f32_16x16x32_bf16(aqf[rt], bkf[ct], zf, 0,0,0);

  // fused bias (16*sigmoid(rpb)+mask), fragment-ordered -> coalesced float4
  const float4v* biasf = (const float4v*)(ws + BIAS_OFF);
  #pragma unroll
  for (int rt = 0; rt < 4; ++rt)
    #pragma unroll
    for (int ct = 0; ct < 4; ++ct) {
      float4v bb = biasf[(size_t)(((w_in*6 + h)*4 + rt)*4 + ct)*64 + lane];
      p[rt][ct][0] += bb[0]; p[rt][ct][1] += bb[1];
      p[rt][ct][2] += bb[2]; p[rt][ct][3] += bb[3];
    }

  // ---- softmax (fp32) + P -> bf16 LDS ----
  #pragma unroll
  for (int rt = 0; rt < 4; ++rt) {
    #pragma unroll
    for (int r = 0; r < 4; ++r) {
      float m = fmaxf(fmaxf(p[rt][0][r], p[rt][1][r]), fmaxf(p[rt][2][r], p[rt][3][r]));
      m = fmaxf(m, __shfl_xor(m,1,16)); m = fmaxf(m, __shfl_xor(m,2,16));
      m = fmaxf(m, __shfl_xor(m,4,16)); m = fmaxf(m, __shfl_xor(m,8,16));
      float e0 = __expf(p[rt][0][r]-m), e1 = __expf(p[rt][1][r]-m);
      float e2 = __expf(p[rt][2][r]-m), e3 = __expf(p[rt][3][r]-m);
      float s = e0+e1+e2+e3;
      s += __shfl_xor(s,1,16); s += __shfl_xor(s,2,16);
      s += __shfl_xor(s,4,16); s += __shfl_xor(s,8,16);
      float inv = 1.f / s;
      int row = 16*rt + 4*lhi + r;
      Ps[row*72 + llo]    = f2bf(e0*inv);
      Ps[row*72 + 16+llo] = f2bf(e1*inv);
      Ps[row*72 + 32+llo] = f2bf(e2*inv);
      Ps[row*72 + 48+llo] = f2bf(e3*inv);
    }
  }

  // ---- PV ----
  short8 apf[4][2], bvf[2][2];
  #pragma unroll
  for (int rt = 0; rt < 4; ++rt)
    #pragma unroll
    for (int ks = 0; ks < 2; ++ks)
      apf[rt][ks] = *(const short8*)(Ps + (16*rt+llo)*72 + ks*32 + 8*lhi);
  #pragma unroll
  for (int ct = 0; ct < 2; ++ct)
    #pragma unroll
    for (int ks = 0; ks < 2; ++ks)
      bvf[ct][ks] = *(const short8*)(vTs + (16*ct+llo)*72 + ks*32 + 8*lhi);
  f32x4 o_[4][2];
  #pragma unroll
  for (int rt = 0; rt < 4; ++rt)
    #pragma unroll
    for (int ct = 0; ct < 2; ++ct) {
      f32x4 t0 = __builtin_amdgcn_mfma_f32_16x16x32_bf16(apf[rt][0], bvf[ct][0], zf, 0,0,0);
      o_[rt][ct] = __builtin_amdgcn_mfma_f32_16x16x32_bf16(apf[rt][1], bvf[ct][1], t0, 0,0,0);
    }

  __syncthreads();   // everyone done with x residual/A-frag reads
  // write o into xb overlay (bf16)
  #pragma unroll
  for (int rt = 0; rt < 4; ++rt)
    #pragma unroll
    for (int ct = 0; ct < 2; ++ct) {
      int col = 32*h + 16*ct + llo;
      #pragma unroll
      for (int r = 0; r < 4; ++r)
        xb[(16*rt + 4*lhi + r)*200 + col] = f2bf(o_[rt][ct][r]);
    }
  __syncthreads();

  // ---- output projection (no residual) ----
  short8 bp[2][3];
  #pragma unroll
  for (int ct = 0; ct < 2; ++ct)
    #pragma unroll
    for (int ks = 0; ks < 3; ++ks)
      bp[ct][ks] = *(const short8*)(ws + (size_t)(((6+half)*6 + cb0+ct)*3 + ks)*1024 + lane*16);
  const float* pbp = half ? p2b : p1b;
  float pbias[2];
  #pragma unroll
  for (int ct = 0; ct < 2; ++ct) pbias[ct] = pbp[16*(cb0+ct) + llo];
  float* og = out + (size_t)b * (NT*DM);
  #pragma unroll
  for (int rt = 0; rt < 4; ++rt) {
    short8 a[3];
    #pragma unroll
    for (int ks = 0; ks < 3; ++ks)
      a[ks] = *(const short8*)(xb + (16*rt + llo)*200 + half*96 + ks*32 + 8*lhi);
    f32x4 ac[2] = {zf, zf};
    #pragma unroll
    for (int ks = 0; ks < 3; ++ks)
      #pragma unroll
      for (int ct = 0; ct < 2; ++ct)
        ac[ct] = __builtin_amdgcn_mfma_f32_16x16x32_bf16(a[ks], bp[ct][ks], ac[ct], 0,0,0);
    #pragma unroll
    for (int ct = 0; ct < 2; ++ct) {
      int col = 32*h + 16*ct + llo;
      #pragma unroll
      for (int r = 0; r < 4; ++r)
        og[(16*rt + 4*lhi + r)*192 + col] = ac[ct][r] + pbias[ct];
    }
  }
}

extern "C" void kernel_launch(void* const* d_in, const int* in_sizes, int n_in,
                              void* d_out, int out_size, void* d_ws, size_t ws_size,
                              hipStream_t stream)
{
  const float* x    = (const float*)d_in[0];
  const float* mask = (const float*)d_in[1];
  const float* ls   = (const float*)d_in[2];
  const float* w1   = (const float*)d_in[3];
  const float* b1   = (const float*)d_in[4];
  const float* w2   = (const float*)d_in[5];
  const float* q1w  = (const float*)d_in[6];  const float* q1b = (const float*)d_in[7];
  const float* q2w  = (const float*)d_in[8];  const float* q2b = (const float*)d_in[9];
  const float* k1w  = (const float*)d_in[10]; const float* k1b = (const float*)d_in[11];
  const float* k2w  = (const float*)d_in[12]; const float* k2b = (const float*)d_in[13];
  const float* v1w  = (const float*)d_in[14]; const float* v1b = (const float*)d_in[15];
  const float* v2w  = (const float*)d_in[16]; const float* v2b = (const float*)d_in[17];
  const float* p1w  = (const float*)d_in[18]; const float* p1b = (const float*)d_in[19];
  const float* p2w  = (const float*)d_in[20]; const float* p2b = (const float*)d_in[21];
  const float* rpbt = (const float*)d_in[22];
  const int*   rpi  = (const int*)d_in[23];
  char* ws = (char*)d_ws;
  float* o = (float*)d_out;

  pre_a<<<49, 256, 0, stream>>>(q1w,q2w,k1w,k2w,v1w,v2w,p1w,p2w, w1,b1,w2, rpbt, ls, ws);
  pre_b<<<384, 256, 0, stream>>>(mask, rpi, ws);

  hipFuncSetAttribute((const void*)win_attn,
                      hipFuncAttributeMaxDynamicSharedMemorySize, 114688);
  win_attn<<<4096, 384, 114688, stream>>>(x, ws, q1b,q2b,k1b,k2b,v1b,v2b,p1b,p2b, o);
}

// Round 4
// 272.289 us; speedup vs baseline: 1.1471x; 1.1471x over previous
//
#include <hip/hip_runtime.h>
#include <hip/hip_bf16.h>

#define NT 64
#define DM 192
#define NH 6

typedef __attribute__((ext_vector_type(4))) float f32x4;
typedef __attribute__((ext_vector_type(8))) short short8;
typedef __attribute__((ext_vector_type(4))) float float4v;
typedef __attribute__((ext_vector_type(2))) unsigned uint2v;
typedef __attribute__((ext_vector_type(8))) unsigned short ushort8v;

// ws layout (bytes)
#define WFRAG_OFF 0
#define BIAS_OFF  147456      // 8*6*3*64*16
#define TAB_OFF   6438912     // BIAS_OFF + 64*6*4*4*64*4*4
#define SCALE_OFF 6444312     // TAB_OFF + 225*6*4

__device__ __forceinline__ unsigned short f2bf(float f){
  unsigned u = __float_as_uint(f);
  u += 0x7fffu + ((u >> 16) & 1u);
  return (unsigned short)(u >> 16);
}
__device__ __forceinline__ float bf2f(unsigned short u){
  return __uint_as_float(((unsigned)u) << 16);
}
// packed f32x2 -> bf16x2 (RNE), 1 instruction
__device__ __forceinline__ unsigned pk2bf(float lo, float hi){
  unsigned r;
  asm("v_cvt_pk_bf16_f32 %0, %1, %2" : "=v"(r) : "v"(lo), "v"(hi));
  return r;
}

// ---------------- precompute A: weight frags + rpb-mlp table + scales ----------------
__global__ __launch_bounds__(256) void pre_a(
  const float* __restrict__ q1w, const float* __restrict__ q2w,
  const float* __restrict__ k1w, const float* __restrict__ k2w,
  const float* __restrict__ v1w, const float* __restrict__ v2w,
  const float* __restrict__ p1w, const float* __restrict__ p2w,
  const float* __restrict__ w1, const float* __restrict__ b1,
  const float* __restrict__ w2, const float* __restrict__ rpbt,
  const float* __restrict__ ls, char* __restrict__ ws)
{
  int blk = blockIdx.x, t = threadIdx.x;
  if (blk < 48) {
    const float* Ws[8] = {q1w,q2w,k1w,k2w,v1w,v2w,p1w,p2w};
    int mat = blk / 6, cb = blk % 6;
    if (t < 192) {
      int lane = t & 63, ks = t >> 6;
      const float* W = Ws[mat];
      int row = (lane & 15) + 16*cb;        // output column (B-col) of this half
      int k0  = 32*ks + 8*(lane >> 4);      // k run
      unsigned short tmp[8];
      #pragma unroll
      for (int i = 0; i < 8; ++i) tmp[i] = f2bf(W[row*96 + k0 + i]);
      *(ushort8v*)(ws + (size_t)((mat*6+cb)*3+ks)*1024 + lane*16) = *(ushort8v*)tmp;
    }
  } else {
    // rpb mlp: 225 positions -> 6 heads
    float* tab = (float*)(ws + TAB_OFF);
    if (t < 225) {
      float t0 = rpbt[2*t], t1 = rpbt[2*t+1];
      float acc[6] = {0,0,0,0,0,0};
      for (int j = 0; j < 128; ++j) {
        float hv = fmaxf(t0*w1[2*j] + t1*w1[2*j+1] + b1[j], 0.f);
        #pragma unroll
        for (int hh = 0; hh < 6; ++hh) acc[hh] += hv * w2[hh*128 + j];
      }
      #pragma unroll
      for (int hh = 0; hh < 6; ++hh) tab[t*6 + hh] = acc[hh];
    }
    if (t >= 240 && t < 246) {
      float* sc = (float*)(ws + SCALE_OFF);
      int i = t - 240;
      sc[i] = expf(fminf(ls[i], 4.605170185988091f)); // log(100)
    }
  }
}

// ---------------- precompute B: fused bias = 16*sigmoid(rpb) + mask, fragment order ----------------
__global__ __launch_bounds__(256) void pre_b(
  const float* __restrict__ mask, const int* __restrict__ rpi,
  char* __restrict__ ws)
{
  int w = blockIdx.x / 6, h = blockIdx.x % 6;
  int lane = threadIdx.x & 63, ct = threadIdx.x >> 6;
  const float* tab = (const float*)(ws + TAB_OFF);
  float* bias = (float*)(ws + BIAS_OFF);
  #pragma unroll
  for (int rt = 0; rt < 4; ++rt)
    #pragma unroll
    for (int r = 0; r < 4; ++r) {
      int i = 16*rt + ((lane >> 4) << 2) + r;   // attn row (C/D frag row)
      int j = 16*ct + (lane & 15);              // attn col (C/D frag col)
      int idx = rpi[i*64 + j];
      float tv = tab[idx*6 + h];
      float sg = 16.f / (1.f + expf(-tv));
      float mv = mask[(w*64 + i)*64 + j];
      bias[(size_t)(((w*6+h)*4+rt)*4+ct)*256 + lane*4 + r] = sg + mv;
    }
}

// ---------------- main fused kernel: 1 block = 1 window, 12 waves = 6 heads x 2 row-splits ----------------
__global__ __launch_bounds__(768, 3) void win_attn(
  const float* __restrict__ x, const char* __restrict__ ws,
  const float* __restrict__ q1b, const float* __restrict__ q2b,
  const float* __restrict__ k1b, const float* __restrict__ k2b,
  const float* __restrict__ v1b, const float* __restrict__ v2b,
  const float* __restrict__ p1b, const float* __restrict__ p2b,
  float* __restrict__ out)
{
  extern __shared__ char smem[];
  unsigned short* xb = (unsigned short*)smem;       // [64][200] bf16 (x, later o)
  const int tid = threadIdx.x;
  const int wv = tid >> 6, lane = tid & 63;
  const int lhi = lane >> 4, llo = lane & 15;
  const int b = blockIdx.x;
  const int w_in = b & 63;

  const int h  = wv >> 1;          // head 0..5
  const int s  = wv & 1;           // row-split 0..1
  const int rt0 = 2*s;             // this wave owns row-tiles rt0, rt0+1

  // per-HEAD scratch (shared by the 2 waves of a head)
  unsigned short* scr = (unsigned short*)(smem + 25600) + (size_t)h * 7424;
  unsigned short* qns = scr;                        // [64][40]
  unsigned short* kns = scr + 2560;                 // [64][40]
  unsigned short* vTs = scr + 5120;                 // [32][72] (v^T)
  unsigned short* Ps  = scr;                        // [64][72] overlays qn+kn

  const int half = (h < 3) ? 0 : 1;
  const int cb0 = (h % 3) * 2;
  const f32x4 zf = {0.f, 0.f, 0.f, 0.f};

  // issue x loads first (coalesced float4, 4 per thread)
  const float* xg = x + (size_t)b * (NT*DM);
  float4v xv[4];
  #pragma unroll
  for (int it = 0; it < 4; ++it) {
    int f4 = tid + it*768;
    xv[it] = *(const float4v*)(xg + 4*f4);
  }

  // weight B-fragments (global, L2-resident, coalesced 16B/lane)
  short8 bq[2][3], bk[2][3], bv[2][3];
  #pragma unroll
  for (int ct = 0; ct < 2; ++ct)
    #pragma unroll
    for (int ks = 0; ks < 3; ++ks) {
      int cb = cb0 + ct;
      bq[ct][ks] = *(const short8*)(ws + (size_t)(((0+half)*6+cb)*3+ks)*1024 + lane*16);
      bk[ct][ks] = *(const short8*)(ws + (size_t)(((2+half)*6+cb)*3+ks)*1024 + lane*16);
      bv[ct][ks] = *(const short8*)(ws + (size_t)(((4+half)*6+cb)*3+ks)*1024 + lane*16);
    }
  const float* qbp = half ? q2b : q1b;
  const float* kbp = half ? k2b : k1b;
  const float* vbp = half ? v2b : v1b;
  float qbias[2], kbias[2], vbias[2];
  #pragma unroll
  for (int ct = 0; ct < 2; ++ct) {
    int cc = 16*(cb0+ct) + llo;
    qbias[ct] = qbp[cc]; kbias[ct] = kbp[cc]; vbias[ct] = vbp[cc];
  }
  float scale_h = ((const float*)(ws + SCALE_OFF))[h];

  // stage x -> LDS bf16 (packed cvt + 8B stores)
  #pragma unroll
  for (int it = 0; it < 4; ++it) {
    int f4 = tid + it*768;
    int row = f4 / 48, c4 = f4 % 48;
    uint2v pk;
    pk[0] = pk2bf(xv[it][0], xv[it][1]);
    pk[1] = pk2bf(xv[it][2], xv[it][3]);
    *(uint2v*)(xb + row*200 + c4*4) = pk;
  }
  __syncthreads();   // (1) x staged

  // ---- Phase A: q,k,v for this head, rows 32s..32s+31 ----
  #pragma unroll
  for (int rr = 0; rr < 2; ++rr) {
    const int rt = rt0 + rr;
    short8 a[3];
    #pragma unroll
    for (int ks = 0; ks < 3; ++ks)
      a[ks] = *(const short8*)(xb + (16*rt + llo)*200 + half*96 + ks*32 + 8*lhi);
    f32x4 aq2[2], ak2[2], av2[2];
    #pragma unroll
    for (int ct = 0; ct < 2; ++ct) { aq2[ct] = zf; ak2[ct] = zf; av2[ct] = zf; }
    #pragma unroll
    for (int ks = 0; ks < 3; ++ks)
      #pragma unroll
      for (int ct = 0; ct < 2; ++ct) {
        aq2[ct] = __builtin_amdgcn_mfma_f32_16x16x32_bf16(a[ks], bq[ct][ks], aq2[ct], 0,0,0);
        ak2[ct] = __builtin_amdgcn_mfma_f32_16x16x32_bf16(a[ks], bk[ct][ks], ak2[ct], 0,0,0);
        av2[ct] = __builtin_amdgcn_mfma_f32_16x16x32_bf16(a[ks], bv[ct][ks], av2[ct], 0,0,0);
      }
    int r0 = 16*rt + 4*lhi;
    float qv[2][4], kv[2][4], vv[2][4];
    #pragma unroll
    for (int ct = 0; ct < 2; ++ct) {
      int colg = 32*h + 16*ct + llo;
      #pragma unroll
      for (int r = 0; r < 4; ++r) {
        float res = bf2f(xb[(r0+r)*200 + colg]);
        qv[ct][r] = aq2[ct][r] + res + qbias[ct];
        kv[ct][r] = ak2[ct][r] + res + kbias[ct];
        vv[ct][r] = av2[ct][r] + res + vbias[ct];
      }
    }
    #pragma unroll
    for (int r = 0; r < 4; ++r) {
      float sq = qv[0][r]*qv[0][r] + qv[1][r]*qv[1][r];
      float sk = kv[0][r]*kv[0][r] + kv[1][r]*kv[1][r];
      sq += __shfl_xor(sq,1,16); sq += __shfl_xor(sq,2,16);
      sq += __shfl_xor(sq,4,16); sq += __shfl_xor(sq,8,16);
      sk += __shfl_xor(sk,1,16); sk += __shfl_xor(sk,2,16);
      sk += __shfl_xor(sk,4,16); sk += __shfl_xor(sk,8,16);
      float invq = scale_h / fmaxf(sqrtf(sq), 1e-12f);  // fold logit scale into qn
      float invk = 1.f / fmaxf(sqrtf(sk), 1e-12f);
      #pragma unroll
      for (int ct = 0; ct < 2; ++ct) {
        qns[(r0+r)*40 + 16*ct + llo] = f2bf(qv[ct][r]*invq);
        kns[(r0+r)*40 + 16*ct + llo] = f2bf(kv[ct][r]*invk);
      }
    }
    // v^T: 4 adjacent tokens -> packed 8B store
    #pragma unroll
    for (int ct = 0; ct < 2; ++ct) {
      uint2v pk;
      pk[0] = pk2bf(vv[ct][0], vv[ct][1]);
      pk[1] = pk2bf(vv[ct][2], vv[ct][3]);
      *(uint2v*)(vTs + (16*ct+llo)*72 + r0) = pk;
    }
  }
  __syncthreads();   // (2) qn/kn/vT ready; all x reads retired

  // ---- QK^T (rows 32s..32s+31), K=32, one MFMA per 16x16 tile ----
  short8 aqf[2], bkf[4];
  #pragma unroll
  for (int rr = 0; rr < 2; ++rr)
    aqf[rr] = *(const short8*)(qns + (16*(rt0+rr) + llo)*40 + 8*lhi);
  #pragma unroll
  for (int i = 0; i < 4; ++i)
    bkf[i] = *(const short8*)(kns + (16*i + llo)*40 + 8*lhi);
  f32x4 p[2][4];
  #pragma unroll
  for (int rr = 0; rr < 2; ++rr)
    #pragma unroll
    for (int ct = 0; ct < 4; ++ct)
      p[rr][ct] = __builtin_amdgcn_mfma_f32_16x16x32_bf16(aqf[rr], bkf[ct], zf, 0,0,0);

  // fused bias (16*sigmoid(rpb)+mask), fragment-ordered -> coalesced float4
  const float4v* biasf = (const float4v*)(ws + BIAS_OFF);
  #pragma unroll
  for (int rr = 0; rr < 2; ++rr)
    #pragma unroll
    for (int ct = 0; ct < 4; ++ct) {
      float4v bb = biasf[(size_t)(((w_in*6 + h)*4 + (rt0+rr))*4 + ct)*64 + lane];
      p[rr][ct][0] += bb[0]; p[rr][ct][1] += bb[1];
      p[rr][ct][2] += bb[2]; p[rr][ct][3] += bb[3];
    }

  // ---- softmax (fp32) into registers ----
  float pn[2][4][4];
  #pragma unroll
  for (int rr = 0; rr < 2; ++rr) {
    #pragma unroll
    for (int r = 0; r < 4; ++r) {
      float m = fmaxf(fmaxf(p[rr][0][r], p[rr][1][r]), fmaxf(p[rr][2][r], p[rr][3][r]));
      m = fmaxf(m, __shfl_xor(m,1,16)); m = fmaxf(m, __shfl_xor(m,2,16));
      m = fmaxf(m, __shfl_xor(m,4,16)); m = fmaxf(m, __shfl_xor(m,8,16));
      float e0 = __expf(p[rr][0][r]-m), e1 = __expf(p[rr][1][r]-m);
      float e2 = __expf(p[rr][2][r]-m), e3 = __expf(p[rr][3][r]-m);
      float sum = e0+e1+e2+e3;
      sum += __shfl_xor(sum,1,16); sum += __shfl_xor(sum,2,16);
      sum += __shfl_xor(sum,4,16); sum += __shfl_xor(sum,8,16);
      float inv = 1.f / sum;
      pn[rr][0][r] = e0*inv; pn[rr][1][r] = e1*inv;
      pn[rr][2][r] = e2*inv; pn[rr][3][r] = e3*inv;
    }
  }
  __syncthreads();   // (3) all qn/kn reads retired -> safe to overlay Ps

  #pragma unroll
  for (int rr = 0; rr < 2; ++rr) {
    int rbase = 16*(rt0+rr) + 4*lhi;
    #pragma unroll
    for (int r = 0; r < 4; ++r) {
      int row = rbase + r;
      Ps[row*72 + llo]    = f2bf(pn[rr][0][r]);
      Ps[row*72 + 16+llo] = f2bf(pn[rr][1][r]);
      Ps[row*72 + 32+llo] = f2bf(pn[rr][2][r]);
      Ps[row*72 + 48+llo] = f2bf(pn[rr][3][r]);
    }
  }
  __syncthreads();   // (4) Ps ready

  // ---- PV ----
  short8 apf[2][2], bvf[2][2];
  #pragma unroll
  for (int rr = 0; rr < 2; ++rr)
    #pragma unroll
    for (int ks = 0; ks < 2; ++ks)
      apf[rr][ks] = *(const short8*)(Ps + (16*(rt0+rr)+llo)*72 + ks*32 + 8*lhi);
  #pragma unroll
  for (int ct = 0; ct < 2; ++ct)
    #pragma unroll
    for (int ks = 0; ks < 2; ++ks)
      bvf[ct][ks] = *(const short8*)(vTs + (16*ct+llo)*72 + ks*32 + 8*lhi);
  f32x4 o_[2][2];
  #pragma unroll
  for (int rr = 0; rr < 2; ++rr)
    #pragma unroll
    for (int ct = 0; ct < 2; ++ct) {
      f32x4 t0 = __builtin_amdgcn_mfma_f32_16x16x32_bf16(apf[rr][0], bvf[ct][0], zf, 0,0,0);
      o_[rr][ct] = __builtin_amdgcn_mfma_f32_16x16x32_bf16(apf[rr][1], bvf[ct][1], t0, 0,0,0);
    }

  // write o into xb overlay (bf16) — x reads all retired at sync (2)
  #pragma unroll
  for (int rr = 0; rr < 2; ++rr)
    #pragma unroll
    for (int ct = 0; ct < 2; ++ct) {
      int col = 32*h + 16*ct + llo;
      #pragma unroll
      for (int r = 0; r < 4; ++r)
        xb[(16*(rt0+rr) + 4*lhi + r)*200 + col] = f2bf(o_[rr][ct][r]);
    }
  __syncthreads();   // (5) o complete from all heads

  // ---- output projection (no residual) ----
  short8 bp[2][3];
  #pragma unroll
  for (int ct = 0; ct < 2; ++ct)
    #pragma unroll
    for (int ks = 0; ks < 3; ++ks)
      bp[ct][ks] = *(const short8*)(ws + (size_t)(((6+half)*6 + cb0+ct)*3 + ks)*1024 + lane*16);
  const float* pbp = half ? p2b : p1b;
  float pbias[2];
  #pragma unroll
  for (int ct = 0; ct < 2; ++ct) pbias[ct] = pbp[16*(cb0+ct) + llo];
  float* og = out + (size_t)b * (NT*DM);
  #pragma unroll
  for (int rr = 0; rr < 2; ++rr) {
    const int rt = rt0 + rr;
    short8 a[3];
    #pragma unroll
    for (int ks = 0; ks < 3; ++ks)
      a[ks] = *(const short8*)(xb + (16*rt + llo)*200 + half*96 + ks*32 + 8*lhi);
    f32x4 ac[2] = {zf, zf};
    #pragma unroll
    for (int ks = 0; ks < 3; ++ks)
      #pragma unroll
      for (int ct = 0; ct < 2; ++ct)
        ac[ct] = __builtin_amdgcn_mfma_f32_16x16x32_bf16(a[ks], bp[ct][ks], ac[ct], 0,0,0);
    #pragma unroll
    for (int ct = 0; ct < 2; ++ct) {
      int col = 32*h + 16*ct + llo;
      #pragma unroll
      for (int r = 0; r < 4; ++r)
        og[(16*rt + 4*lhi + r)*192 + col] = ac[ct][r] + pbias[ct];
    }
  }
}

extern "C" void kernel_launch(void* const* d_in, const int* in_sizes, int n_in,
                              void* d_out, int out_size, void* d_ws, size_t ws_size,
                              hipStream_t stream)
{
  const float* x    = (const float*)d_in[0];
  const float* mask = (const float*)d_in[1];
  const float* ls   = (const float*)d_in[2];
  const float* w1   = (const float*)d_in[3];
  const float* b1   = (const float*)d_in[4];
  const float* w2   = (const float*)d_in[5];
  const float* q1w  = (const float*)d_in[6];  const float* q1b = (const float*)d_in[7];
  const float* q2w  = (const float*)d_in[8];  const float* q2b = (const float*)d_in[9];
  const float* k1w  = (const float*)d_in[10]; const float* k1b = (const float*)d_in[11];
  const float* k2w  = (const float*)d_in[12]; const float* k2b = (const float*)d_in[13];
  const float* v1w  = (const float*)d_in[14]; const float* v1b = (const float*)d_in[15];
  const float* v2w  = (const float*)d_in[16]; const float* v2b = (const float*)d_in[17];
  const float* p1w  = (const float*)d_in[18]; const float* p1b = (const float*)d_in[19];
  const float* p2w  = (const float*)d_in[20]; const float* p2b = (const float*)d_in[21];
  const float* rpbt = (const float*)d_in[22];
  const int*   rpi  = (const int*)d_in[23];
  char* ws = (char*)d_ws;
  float* o = (float*)d_out;

  pre_a<<<49, 256, 0, stream>>>(q1w,q2w,k1w,k2w,v1w,v2w,p1w,p2w, w1,b1,w2, rpbt, ls, ws);
  pre_b<<<384, 256, 0, stream>>>(mask, rpi, ws);

  hipFuncSetAttribute((const void*)win_attn,
                      hipFuncAttributeMaxDynamicSharedMemorySize, 114688);
  win_attn<<<4096, 768, 114688, stream>>>(x, ws, q1b,q2b,k1b,k2b,v1b,v2b,p1b,p2b, o);
}